// Round 1
// 112.896 us; speedup vs baseline: 1.0888x; 1.0888x over previous
//
#include <hip/hip_runtime.h>

// SpatialAttention: B=4, C=256, H=W=64 -> N=4096, C_qk=32
// d_out: [output (4*256*4096)] ++ [attention_map (4*4096)]  (fp32)
//
// R7: atomic-free two-pass softmax stats.
//  - k_prep: 1024 blocks x 16 tokens; all 4 waves project q/k; out=x copy.
//    q pre-scaled by log2(e) so both passes use raw v_exp_f32 (2^x).
//  - k_rowsA: block owns 32 FULL rows (8 waves x 512-col slices); LDS
//    cross-wave reduce; writes l[i] AND llog[i] = -log2(l_i) directly.
//  - k_mapB: block owns 32 FULL cols; C-init = llog broadcast; writes map
//    directly. No atomics anywhere on the gamma==0 path; no zero-init pass.
//  - k_pv (gamma != 0 only) unchanged.

#define B_   4
#define C_   256
#define N_   4096
#define CQK_ 32
#define BCN_ (B_*C_*N_)   // 4194304
#define BN_  (B_*N_)      // 16384
#define TP_  260          // LDS token-row pitch (ushorts); 520B -> conflict-light
#define LOG2E 1.4426950408889634f

typedef __attribute__((ext_vector_type(8))) short short8v;
typedef __attribute__((ext_vector_type(4))) short short4v;
typedef __attribute__((ext_vector_type(4))) float f32x4;
typedef unsigned short ushort_t;

__device__ __forceinline__ ushort_t f2bf(float f) {
  unsigned u = __builtin_bit_cast(unsigned, f);
  u += 0x7FFFu + ((u >> 16) & 1u);          // round-to-nearest-even
  return (ushort_t)(u >> 16);
}
__device__ __forceinline__ float bf2f(ushort_t h) {
  unsigned u = ((unsigned)h) << 16;
  return __builtin_bit_cast(float, u);
}
__device__ __forceinline__ short8v ld8f(const float* p) {   // 8 fp32 -> bf16 frag
  float4 a = *(const float4*)p, b = *(const float4*)(p + 4);
  short8v r;
  r[0]=f2bf(a.x); r[1]=f2bf(a.y); r[2]=f2bf(a.z); r[3]=f2bf(a.w);
  r[4]=f2bf(b.x); r[5]=f2bf(b.y); r[6]=f2bf(b.z); r[7]=f2bf(b.w);
  return r;
}
__device__ __forceinline__ short8v ld8lds(const ushort_t* p) {  // 8B-aligned LDS
  short4v lo = *(const short4v*)p, hi = *(const short4v*)(p + 4);
  return __builtin_shufflevector(lo, hi, 0, 1, 2, 3, 4, 5, 6, 7);
}

// ---- fused prep+proj: out=x, q/k (+v) projections -------------------------
// grid 1024: b(4) x tg(256: 16-token groups). LDS: 16 tokens x 256 ch bf16.
__global__ __launch_bounds__(256) void
k_prep(const float* __restrict__ x,
       const float* __restrict__ wq, const float* __restrict__ bq,
       const float* __restrict__ wk, const float* __restrict__ bk,
       const float* __restrict__ wv, const float* __restrict__ bv,
       const float* __restrict__ gamma,
       float* __restrict__ out,
       ushort_t* __restrict__ qb, ushort_t* __restrict__ kb,
       float* __restrict__ v_t) {
  __shared__ ushort_t xs[16 * TP_];
  int blk = blockIdx.x, tid = threadIdx.x;
  int b = blk >> 8, n0 = (blk & 255) << 4;
#pragma unroll
  for (int it = 0; it < 4; ++it) {            // stage 256ch x 16tok + out=x
    int flat = it * 256 + tid;                // 1024 float4s
    int c = flat >> 2, t4 = flat & 3;
    size_t off = ((size_t)(b * C_) + c) * N_ + n0 + t4 * 4;
    float4 v = *(const float4*)(x + off);
    *(float4*)(out + off) = v;
    ushort_t* dst = &xs[(t4 * 4) * TP_ + c];
    dst[0]        = f2bf(v.x);
    dst[TP_]      = f2bf(v.y);
    dst[2 * TP_]  = f2bf(v.z);
    dst[3 * TP_]  = f2bf(v.w);
  }
  __syncthreads();

  int wave = tid >> 6, lane = tid & 63;
  int col16 = lane & 15, quad = lane >> 4;
  bool isq = wave < 2;
  int mt = wave & 1;                          // 16-outch tile within C_qk
  short8v bfr[8];
#pragma unroll
  for (int ks = 0; ks < 8; ++ks)
    bfr[ks] = ld8lds(&xs[col16 * TP_ + ks * 32 + quad * 8]);

  const float* wrow = isq ? wq : wk;
  const float* bias = isq ? bq : bk;
  ushort_t* dst = isq ? qb : kb;
  f32x4 c = {0.f, 0.f, 0.f, 0.f};
#pragma unroll
  for (int ks = 0; ks < 8; ++ks) {
    short8v afr = ld8f(wrow + (mt * 16 + col16) * C_ + ks * 32 + quad * 8);
    c = __builtin_amdgcn_mfma_f32_16x16x32_bf16(afr, bfr[ks], c, 0, 0, 0);
  }
  int co = mt * 16 + quad * 4;
  ushort4 pk;
  if (isq) {                                  // q pre-scaled by log2(e)
    pk.x = f2bf((c[0] + bias[co + 0]) * LOG2E);
    pk.y = f2bf((c[1] + bias[co + 1]) * LOG2E);
    pk.z = f2bf((c[2] + bias[co + 2]) * LOG2E);
    pk.w = f2bf((c[3] + bias[co + 3]) * LOG2E);
  } else {
    pk.x = f2bf(c[0] + bias[co + 0]); pk.y = f2bf(c[1] + bias[co + 1]);
    pk.z = f2bf(c[2] + bias[co + 2]); pk.w = f2bf(c[3] + bias[co + 3]);
  }
  *(ushort4*)(dst + ((size_t)(b * N_) + n0 + col16) * CQK_ + co) = pk;

  if (gamma[0] != 0.0f) {                     // v projection (gamma != 0 only)
#pragma unroll
    for (int vt = 0; vt < 4; ++vt) {
      int tile = wave * 4 + vt;               // 16 tiles over 4 waves
      f32x4 cv = {0.f, 0.f, 0.f, 0.f};
#pragma unroll
      for (int ks = 0; ks < 8; ++ks) {
        short8v afr = ld8f(wv + (tile * 16 + col16) * C_ + ks * 32 + quad * 8);
        cv = __builtin_amdgcn_mfma_f32_16x16x32_bf16(afr, bfr[ks], cv, 0, 0, 0);
      }
      int cvo = tile * 16 + quad * 4;
      float4 o;
      o.x = cv[0] + bv[cvo];     o.y = cv[1] + bv[cvo + 1];
      o.z = cv[2] + bv[cvo + 2]; o.w = cv[3] + bv[cvo + 3];
      *(float4*)(v_t + ((size_t)(b * N_) + n0 + col16) * C_ + cvo) = o;
    }
  }
}

// ---- pass A: l[b,i] = sum_j 2^(S'_ij); llog = -log2(l). Atomic-free. ------
// grid 512: b(4) x rg(128: 32-row groups). 512 thr = 8 waves x 512-col slices.
__global__ __launch_bounds__(512) void
k_rowsA(const ushort_t* __restrict__ qb, const ushort_t* __restrict__ kb,
        float* __restrict__ l, float* __restrict__ llog) {
  __shared__ float red[8][32];
  int blk = blockIdx.x;
  int b = blk >> 7, rg = blk & 127;
  int tid = threadIdx.x, wave = tid >> 6, lane = tid & 63;
  int col16 = lane & 15, quad = lane >> 4;
  const ushort_t* qbb = qb + (size_t)b * N_ * CQK_;
  const ushort_t* kbb = kb + (size_t)b * N_ * CQK_;
  int i_base = rg * 32;
  short8v a0 = *(const short8v*)(qbb + (size_t)(i_base + col16) * CQK_ + quad * 8);
  short8v a1 = *(const short8v*)(qbb + (size_t)(i_base + 16 + col16) * CQK_ + quad * 8);
  float racc[8];
#pragma unroll
  for (int r = 0; r < 8; ++r) racc[r] = 0.0f;
  const f32x4 z = {0.f, 0.f, 0.f, 0.f};
  const ushort_t* kp = kbb + (size_t)(wave * 512 + col16) * CQK_ + quad * 8;
#pragma unroll 4
  for (int t = 0; t < 32; ++t) {
    short8v bfr = *(const short8v*)(kp + (size_t)t * 16 * CQK_);
    f32x4 c0 = __builtin_amdgcn_mfma_f32_16x16x32_bf16(a0, bfr, z, 0, 0, 0);
    f32x4 c1 = __builtin_amdgcn_mfma_f32_16x16x32_bf16(a1, bfr, z, 0, 0, 0);
    racc[0] += __builtin_amdgcn_exp2f(c0[0]);
    racc[1] += __builtin_amdgcn_exp2f(c0[1]);
    racc[2] += __builtin_amdgcn_exp2f(c0[2]);
    racc[3] += __builtin_amdgcn_exp2f(c0[3]);
    racc[4] += __builtin_amdgcn_exp2f(c1[0]);
    racc[5] += __builtin_amdgcn_exp2f(c1[1]);
    racc[6] += __builtin_amdgcn_exp2f(c1[2]);
    racc[7] += __builtin_amdgcn_exp2f(c1[3]);
  }
#pragma unroll
  for (int r = 0; r < 8; ++r) {               // reduce over cols (lane&15)
    float v = racc[r];
    v += __shfl_xor(v, 1); v += __shfl_xor(v, 2);
    v += __shfl_xor(v, 4); v += __shfl_xor(v, 8);
    racc[r] = v;
  }
  if (col16 == 0) {
#pragma unroll
    for (int m = 0; m < 2; ++m)
#pragma unroll
      for (int rr = 0; rr < 4; ++rr)
        red[wave][m * 16 + quad * 4 + rr] = racc[m * 4 + rr];
  }
  __syncthreads();
  if (tid < 32) {                             // cross-wave reduce, direct store
    float s = 0.0f;
#pragma unroll
    for (int w = 0; w < 8; ++w) s += red[w][tid];
    l[b * N_ + i_base + tid] = s;
    llog[b * N_ + i_base + tid] = -__builtin_amdgcn_logf(s);
  }
}

// ---- pass B: map[j] = (1/N) sum_i 2^(S'_ij + llog_i). Atomic-free. --------
// grid 512: b(4) x jg(128: 32-col groups). 512 thr = 8 waves x 512-row slices.
__global__ __launch_bounds__(512) void
k_mapB(const ushort_t* __restrict__ qb, const ushort_t* __restrict__ kb,
       const float* __restrict__ llog, float* __restrict__ map) {
  __shared__ float red[8][32];
  int blk = blockIdx.x;
  int b = blk >> 7, jg = blk & 127;
  int tid = threadIdx.x, wave = tid >> 6, lane = tid & 63;
  int col16 = lane & 15, quad = lane >> 4;
  const ushort_t* qbb = qb + (size_t)b * N_ * CQK_;
  const ushort_t* kbb = kb + (size_t)b * N_ * CQK_;
  int j_base = jg * 32;
  short8v a0 = *(const short8v*)(kbb + (size_t)(j_base + col16) * CQK_ + quad * 8);
  short8v a1 = *(const short8v*)(kbb + (size_t)(j_base + 16 + col16) * CQK_ + quad * 8);
  float csum[8];
#pragma unroll
  for (int r = 0; r < 8; ++r) csum[r] = 0.0f;
  const float* lp = llog + b * N_ + wave * 512 + col16;
  const ushort_t* qp = qbb + (size_t)(wave * 512 + col16) * CQK_ + quad * 8;
#pragma unroll 4
  for (int t = 0; t < 32; ++t) {
    short8v bfr = *(const short8v*)(qp + (size_t)t * 16 * CQK_);
    float ll = lp[t * 16];                    // -log2(l_i), i = lane col
    f32x4 ci = {ll, ll, ll, ll};              // D cols = i -> fold 1/l_i here
    f32x4 c0 = __builtin_amdgcn_mfma_f32_16x16x32_bf16(a0, bfr, ci, 0, 0, 0);
    f32x4 c1 = __builtin_amdgcn_mfma_f32_16x16x32_bf16(a1, bfr, ci, 0, 0, 0);
    csum[0] += __builtin_amdgcn_exp2f(c0[0]);
    csum[1] += __builtin_amdgcn_exp2f(c0[1]);
    csum[2] += __builtin_amdgcn_exp2f(c0[2]);
    csum[3] += __builtin_amdgcn_exp2f(c0[3]);
    csum[4] += __builtin_amdgcn_exp2f(c1[0]);
    csum[5] += __builtin_amdgcn_exp2f(c1[1]);
    csum[6] += __builtin_amdgcn_exp2f(c1[2]);
    csum[7] += __builtin_amdgcn_exp2f(c1[3]);
  }
#pragma unroll
  for (int r = 0; r < 8; ++r) {               // reduce over i (lane&15)
    float v = csum[r];
    v += __shfl_xor(v, 1); v += __shfl_xor(v, 2);
    v += __shfl_xor(v, 4); v += __shfl_xor(v, 8);
    csum[r] = v;
  }
  if (col16 == 0) {
#pragma unroll
    for (int m = 0; m < 2; ++m)
#pragma unroll
      for (int rr = 0; rr < 4; ++rr)
        red[wave][m * 16 + quad * 4 + rr] = csum[m * 4 + rr];
  }
  __syncthreads();
  if (tid < 32) {
    float s = 0.0f;
#pragma unroll
    for (int w = 0; w < 8; ++w) s += red[w][tid];
    map[b * N_ + j_base + tid] = s * (1.0f / (float)N_);
  }
}

// ---- PV + residual add (gamma != 0 only); qb is pre-scaled -> use 2^x -------
__global__ __launch_bounds__(256) void
k_pv(const ushort_t* __restrict__ qb, const ushort_t* __restrict__ kb,
     const float* __restrict__ v_t, const float* __restrict__ l,
     const float* __restrict__ gamma, float* __restrict__ out) {
  if (gamma[0] == 0.0f) return;
  __shared__ float qs[32 * CQK_];
  __shared__ float invl[32];
  __shared__ float ps[32 * 256];
  int blk = blockIdx.x;
  int b = blk >> 9, i0 = ((blk >> 2) & 127) << 5, jsp = blk & 3;
  int tid = threadIdx.x;
  for (int r = tid; r < 32 * CQK_; r += 256)
    qs[r] = bf2f(qb[((size_t)(b * N_) + i0) * CQK_ + r]);
  if (tid < 32) invl[tid] = 1.0f / l[b * N_ + i0 + tid];
  __syncthreads();
  float g = gamma[0];
  float acc[32];
#pragma unroll
  for (int i = 0; i < 32; ++i) acc[i] = 0.0f;
  for (int jt = jsp * 4; jt < jsp * 4 + 4; ++jt) {
    int j = jt * 256 + tid;
    const ushort_t* krow = kb + ((size_t)(b * N_) + j) * CQK_;
    float kcol[CQK_];
#pragma unroll
    for (int o = 0; o < CQK_; ++o) kcol[o] = bf2f(krow[o]);
#pragma unroll
    for (int i = 0; i < 32; ++i) {
      float s = 0.0f;
#pragma unroll
      for (int o = 0; o < CQK_; ++o) s += qs[i * CQK_ + o] * kcol[o];
      ps[i * 256 + tid] = __builtin_amdgcn_exp2f(s) * invl[i];
    }
    __syncthreads();
    const float* vtb = v_t + ((size_t)(b * N_) + jt * 256) * C_;
    for (int jj = 0; jj < 256; ++jj) {
      float vv = vtb[(size_t)jj * C_ + tid];
#pragma unroll
      for (int i = 0; i < 32; ++i) acc[i] += ps[i * 256 + jj] * vv;
    }
    __syncthreads();
  }
  float* ob = out + ((size_t)(b * C_) + tid) * N_ + i0;
#pragma unroll
  for (int i = 0; i < 32; ++i) atomicAdd(&ob[i], g * acc[i]);
}

extern "C" void kernel_launch(void* const* d_in, const int* in_sizes, int n_in,
                              void* d_out, int out_size, void* d_ws, size_t ws_size,
                              hipStream_t stream) {
  const float* x     = (const float*)d_in[0];
  const float* wq    = (const float*)d_in[1];
  const float* bq    = (const float*)d_in[2];
  const float* wk    = (const float*)d_in[3];
  const float* bk    = (const float*)d_in[4];
  const float* wv    = (const float*)d_in[5];
  const float* bv    = (const float*)d_in[6];
  const float* gamma = (const float*)d_in[7];
  float* out = (float*)d_out;
  float* wsf = (float*)d_ws;
  // ws layout (float offsets): l 16384 | llog 16384 | qb 262144 | kb 262144 | v_t
  float*    l    = wsf;
  float*    llog = wsf + 16384;
  ushort_t* qb   = (ushort_t*)(wsf + 32768);
  ushort_t* kb   = (ushort_t*)(wsf + 32768 + 262144);
  float*    v_t  = wsf + 32768 + 2 * 262144;

  k_prep <<<1024, 256, 0, stream>>>(x, wq, bq, wk, bk, wv, bv, gamma,
                                    out, qb, kb, v_t);
  k_rowsA<<< 512, 512, 0, stream>>>(qb, kb, l, llog);
  k_mapB <<< 512, 512, 0, stream>>>(qb, kb, llog, out + BCN_);
  k_pv   <<<2048, 256, 0, stream>>>(qb, kb, v_t, l, gamma, out);
}